// Round 6
// baseline (395.464 us; speedup 1.0000x reference)
//
#include <hip/hip_runtime.h>
#include <hip/hip_bf16.h>

typedef __bf16 bf16x8 __attribute__((ext_vector_type(8)));
typedef float f32x4 __attribute__((ext_vector_type(4)));
typedef float f32x2 __attribute__((ext_vector_type(2)));

#define CC 256
#define MT1 64   // tokens per K1 block
#define MT2 32   // tokens per K2 block

// swizzled LDS byte offset for element (r, c) of a [.][256] bf16 tile
__device__ __forceinline__ int swz(int r, int c) {
    return r * 512 + ((c * 2) ^ ((r & 7) << 4));
}

// A-fragment straight from global fp32 (row-major [.][256]), converted to bf16.
// lane pattern: row = tile_row + r16, k = k0 + q4*8 .. +8  -> 2x16B loads.
__device__ __forceinline__ bf16x8 afrag(const float* __restrict__ src, int row, int k0) {
    f32x4 v0 = *(const f32x4*)(src + (size_t)row * CC + k0);
    f32x4 v1 = *(const f32x4*)(src + (size_t)row * CC + k0 + 4);
    bf16x8 a;
    a[0] = (__bf16)v0[0]; a[1] = (__bf16)v0[1]; a[2] = (__bf16)v0[2]; a[3] = (__bf16)v0[3];
    a[4] = (__bf16)v1[0]; a[5] = (__bf16)v1[1]; a[6] = (__bf16)v1[2]; a[7] = (__bf16)v1[3];
    return a;
}

// weight prep: transpose + bf16 convert. layout (bf16 elem offsets):
//   WTqp @0 [256][512] (k<256: Wq, k>=256: Wpos) | WTkp @131072 [256][512]
//   WTo1 @262144 [512][256] | WTo2 @393216 [64][512] | WTv @425984 [256][256]
//   WTout @491520 [256][256]   (total 557056 bf16 = 1114112 B)
__global__ void prep_all(const float* __restrict__ Wq, const float* __restrict__ Wk,
                         const float* __restrict__ Wpos, const float* __restrict__ Wo1,
                         const float* __restrict__ Wo2, const float* __restrict__ Wv,
                         const float* __restrict__ Wout, __bf16* __restrict__ ws)
{
    int i = blockIdx.x * 256 + threadIdx.x;
    if (i >= 557056) return;
    float v;
    if (i < 131072) {
        int n = i >> 9, k = i & 511;
        v = (k < 256) ? Wq[k * 256 + n] : Wpos[(k - 256) * 256 + n];
    } else if (i < 262144) {
        int j = i - 131072, n = j >> 9, k = j & 511;
        v = (k < 256) ? Wk[k * 256 + n] : Wpos[(k - 256) * 256 + n];
    } else if (i < 393216) {
        int j = i - 262144, n = j >> 8, k = j & 255;
        v = Wo1[k * 512 + n];
    } else if (i < 425984) {
        int j = i - 393216, n = j >> 9, k = j & 511;
        v = Wo2[k * 64 + n];
    } else if (i < 491520) {
        int j = i - 425984, n = j >> 8, k = j & 255;
        v = Wv[k * 256 + n];
    } else {
        int j = i - 491520, n = j >> 8, k = j & 255;
        v = Wout[k * 256 + n];
    }
    ws[i] = (__bf16)v;
}

// ============ K1: query/key/pose -> wv [L*8 floats] ============
// No activation staging; q/k never materialized (wave-local head dot).
extern "C" __global__ void __launch_bounds__(256, 2)
k1_attn_weights(const float* __restrict__ query, const float* __restrict__ key,
                const float* __restrict__ pose, const float* __restrict__ refp,
                const __bf16* __restrict__ ws,
                const float* __restrict__ bq, const float* __restrict__ bk,
                const float* __restrict__ bpos, const float* __restrict__ bo1,
                const float* __restrict__ bo2,
                float* __restrict__ wv_g)
{
    const __bf16* WTqp = ws;
    const __bf16* WTkp = ws + 131072;
    const __bf16* WTo1 = ws + 262144;
    const __bf16* WTo2 = ws + 393216;

    __shared__ __attribute__((aligned(16))) __bf16 h1_lds[MT1 * 256];  // 32 KB
    __shared__ float off_s[MT1 * 64];                                  // 16 KB
    __shared__ float qk_s[MT1 * 8];                                    // 2 KB

    const int tid = threadIdx.x;
    const int lane = tid & 63;
    const int wid = tid >> 6;
    const int r16 = lane & 15;
    const int q4 = lane >> 4;
    const int row0 = blockIdx.x * MT1;

    f32x4 accO[4];   // off-GEMM accumulator [mf], persists across both h1 passes
#pragma unroll
    for (int i = 0; i < 4; ++i) accO[i] = (f32x4){0.f, 0.f, 0.f, 0.f};

    // ---- h1 (two 256-col passes) + off partial ----
    for (int p = 0; p < 2; ++p) {
        f32x4 acc[4][4];
#pragma unroll
        for (int i = 0; i < 4; ++i)
#pragma unroll
            for (int j = 0; j < 4; ++j) acc[i][j] = (f32x4){0.f, 0.f, 0.f, 0.f};
#pragma unroll
        for (int ks = 0; ks < 8; ++ks) {
            int k0 = ks * 32 + q4 * 8;
            bf16x8 a[4], b[4];
#pragma unroll
            for (int mf = 0; mf < 4; ++mf)
                a[mf] = afrag(query, row0 + mf * 16 + r16, k0);
#pragma unroll
            for (int nf = 0; nf < 4; ++nf) {
                int col = p * 256 + wid * 64 + nf * 16 + r16;
                b[nf] = *(const bf16x8*)(WTo1 + (size_t)col * 256 + k0);
            }
#pragma unroll
            for (int mf = 0; mf < 4; ++mf)
#pragma unroll
                for (int nf = 0; nf < 4; ++nf)
                    acc[mf][nf] = __builtin_amdgcn_mfma_f32_16x16x32_bf16(a[mf], b[nf], acc[mf][nf], 0, 0, 0);
        }
        // relu + bias -> h1_lds (local cols = wave's 64-col slice)
#pragma unroll
        for (int mf = 0; mf < 4; ++mf)
#pragma unroll
            for (int nf = 0; nf < 4; ++nf) {
                int lcol = wid * 64 + nf * 16 + r16;
                float bias = bo1[p * 256 + lcol];
#pragma unroll
                for (int r = 0; r < 4; ++r)
                    *(__bf16*)((char*)h1_lds + swz(mf * 16 + q4 * 4 + r, lcol)) =
                        (__bf16)fmaxf(acc[mf][nf][r] + bias, 0.f);
            }
        __syncthreads();
        // off partial: wave owns off-cols [16w,16w+16), K over this pass's 256 h1-cols
        {
            int col = wid * 16 + r16;
#pragma unroll
            for (int ks = 0; ks < 8; ++ks) {
                int k0 = ks * 32 + q4 * 8;
                bf16x8 b = *(const bf16x8*)(WTo2 + (size_t)col * 512 + p * 256 + k0);
#pragma unroll
                for (int mf = 0; mf < 4; ++mf) {
                    bf16x8 a = *(const bf16x8*)((const char*)h1_lds + swz(mf * 16 + r16, k0));
                    accO[mf] = __builtin_amdgcn_mfma_f32_16x16x32_bf16(a, b, accO[mf], 0, 0, 0);
                }
            }
        }
        __syncthreads();   // h1_lds reads done before next pass overwrites
    }
    // write off_s
    {
        int col = wid * 16 + r16;
        float b2 = bo2[col];
#pragma unroll
        for (int mf = 0; mf < 4; ++mf)
#pragma unroll
            for (int r = 0; r < 4; ++r)
                off_s[(mf * 16 + q4 * 4 + r) * 64 + col] = accO[mf][r] + b2;
    }

    // ---- q,k combined GEMM (K=512, pose fragments shared) + wave-local head dot ----
    {
        f32x4 qa[4][4], ka[4][4];
#pragma unroll
        for (int i = 0; i < 4; ++i)
#pragma unroll
            for (int j = 0; j < 4; ++j) {
                qa[i][j] = (f32x4){0.f, 0.f, 0.f, 0.f};
                ka[i][j] = (f32x4){0.f, 0.f, 0.f, 0.f};
            }
#pragma unroll
        for (int ks = 0; ks < 8; ++ks) {
            int k0 = ks * 32 + q4 * 8;
            bf16x8 aq[4], ak[4], b[4];
#pragma unroll
            for (int mf = 0; mf < 4; ++mf)
                aq[mf] = afrag(query, row0 + mf * 16 + r16, k0);
#pragma unroll
            for (int nf = 0; nf < 4; ++nf)
                b[nf] = *(const bf16x8*)(WTqp + (size_t)(wid * 64 + nf * 16 + r16) * 512 + k0);
#pragma unroll
            for (int mf = 0; mf < 4; ++mf)
#pragma unroll
                for (int nf = 0; nf < 4; ++nf)
                    qa[mf][nf] = __builtin_amdgcn_mfma_f32_16x16x32_bf16(aq[mf], b[nf], qa[mf][nf], 0, 0, 0);
#pragma unroll
            for (int mf = 0; mf < 4; ++mf)
                ak[mf] = afrag(key, row0 + mf * 16 + r16, k0);
#pragma unroll
            for (int nf = 0; nf < 4; ++nf)
                b[nf] = *(const bf16x8*)(WTkp + (size_t)(wid * 64 + nf * 16 + r16) * 512 + k0);
#pragma unroll
            for (int mf = 0; mf < 4; ++mf)
#pragma unroll
                for (int nf = 0; nf < 4; ++nf)
                    ka[mf][nf] = __builtin_amdgcn_mfma_f32_16x16x32_bf16(ak[mf], b[nf], ka[mf][nf], 0, 0, 0);
        }
#pragma unroll
        for (int ks = 8; ks < 16; ++ks) {
            int k0 = ks * 32 + q4 * 8;
            bf16x8 ap[4], bqf[4], bkf[4];
#pragma unroll
            for (int mf = 0; mf < 4; ++mf)
                ap[mf] = afrag(pose, row0 + mf * 16 + r16, k0 - 256);
#pragma unroll
            for (int nf = 0; nf < 4; ++nf) {
                bqf[nf] = *(const bf16x8*)(WTqp + (size_t)(wid * 64 + nf * 16 + r16) * 512 + k0);
                bkf[nf] = *(const bf16x8*)(WTkp + (size_t)(wid * 64 + nf * 16 + r16) * 512 + k0);
            }
#pragma unroll
            for (int mf = 0; mf < 4; ++mf)
#pragma unroll
                for (int nf = 0; nf < 4; ++nf) {
                    qa[mf][nf] = __builtin_amdgcn_mfma_f32_16x16x32_bf16(ap[mf], bqf[nf], qa[mf][nf], 0, 0, 0);
                    ka[mf][nf] = __builtin_amdgcn_mfma_f32_16x16x32_bf16(ap[mf], bkf[nf], ka[mf][nf], 0, 0, 0);
                }
        }
        // biases per col, then head dot: wave cols = heads {2w, 2w+1}
        float Bq[4], Bk[4];
#pragma unroll
        for (int nf = 0; nf < 4; ++nf) {
            int col = wid * 64 + nf * 16 + r16;
            Bq[nf] = bq[col] + bpos[col];
            Bk[nf] = bk[col] + bpos[col];
        }
#pragma unroll
        for (int mf = 0; mf < 4; ++mf)
#pragma unroll
            for (int r = 0; r < 4; ++r) {
                float p0 = (qa[mf][0][r] + Bq[0]) * (ka[mf][0][r] + Bk[0])
                         + (qa[mf][1][r] + Bq[1]) * (ka[mf][1][r] + Bk[1]);
                float p1 = (qa[mf][2][r] + Bq[2]) * (ka[mf][2][r] + Bk[2])
                         + (qa[mf][3][r] + Bq[3]) * (ka[mf][3][r] + Bk[3]);
#pragma unroll
                for (int m = 1; m < 16; m <<= 1) {
                    p0 += __shfl_xor(p0, m);
                    p1 += __shfl_xor(p1, m);
                }
                if (r16 == 0) {
                    int row = mf * 16 + q4 * 4 + r;
                    qk_s[row * 8 + wid * 2]     = p0;
                    qk_s[row * 8 + wid * 2 + 1] = p1;
                }
            }
    }
    __syncthreads();   // qk_s + off_s visible

    // ---- softmax -> wv (2 (t,h) pairs per thread) ----
#pragma unroll
    for (int pi = 0; pi < 2; ++pi) {
        int idx = tid + pi * 256;
        int t = idx >> 3, h = idx & 7;
        float qk = qk_s[t * 8 + h];
        f32x2 rp = __builtin_nontemporal_load((const f32x2*)(refp + (size_t)(row0 + t) * 2));
        float wgt[4], lg[4];
        float m = -1e30f;
#pragma unroll
        for (int kk = 0; kk < 4; ++kk) {
            float2 o = *(const float2*)&off_s[t * 64 + (h * 4 + kk) * 2];
            float cx = rp[0] + o.x - 0.5f, cy = rp[1] + o.y - 0.5f;
            float wx = fmaxf(0.f, 1.f - fabsf(cx));
            float wy = fmaxf(0.f, 1.f - fabsf(cy));
            wgt[kk] = wx * wy;
            lg[kk] = qk * wgt[kk] * 0.17677669529663687f;  // 1/sqrt(32)
            m = fmaxf(m, lg[kk]);
        }
        float s = 0.f, sw = 0.f;
#pragma unroll
        for (int kk = 0; kk < 4; ++kk) {
            float e = __expf(lg[kk] - m);
            s += e;
            sw += e * wgt[kk];
        }
        __builtin_nontemporal_store(sw / s, wv_g + (size_t)(row0 + t) * 8 + h);
    }
}

// ============ K2: value + wv -> out ============
__device__ __forceinline__ void zero24(f32x4 (&acc)[2][4]) {
#pragma unroll
    for (int i = 0; i < 2; ++i)
#pragma unroll
        for (int j = 0; j < 4; ++j)
            acc[i][j] = (f32x4){0.f, 0.f, 0.f, 0.f};
}

extern "C" __global__ void __launch_bounds__(256, 4)
k2_output(const float* __restrict__ value, const float* __restrict__ wv_g,
          const __bf16* __restrict__ ws,
          const float* __restrict__ bv, const float* __restrict__ bout,
          float* __restrict__ out)
{
    const __bf16* WTv   = ws + 425984;
    const __bf16* WTout = ws + 491520;

    __shared__ __attribute__((aligned(16))) __bf16 SC[MT2 * 256];  // value
    __shared__ __attribute__((aligned(16))) __bf16 SD[MT2 * 256];  // o = v*wv
    __shared__ float wv_s[MT2 * 8];

    const int tid = threadIdx.x;
    const int lane = tid & 63;
    const int wid = tid >> 6;
    const int r16 = lane & 15;
    const int q4 = lane >> 4;
    const int row0 = blockIdx.x * MT2;
    const int cb = wid * 64;

    f32x4 acc[2][4];

    // P1: stage value -> SC (nt loads), wv tile -> wv_s
    {
        f32x4 vv[8];
#pragma unroll
        for (int i = 0; i < 8; ++i) {
            int f = i * 256 + tid;
            int r = f >> 6;
            int c = (f & 63) * 4;
            vv[i] = __builtin_nontemporal_load((const f32x4*)(value + (size_t)(row0 + r) * CC + c));
        }
        wv_s[tid] = wv_g[(size_t)row0 * 8 + tid];
#pragma unroll
        for (int i = 0; i < 8; ++i) {
            int f = i * 256 + tid;
            int r = f >> 6;
            int c = (f & 63) * 4;
            union { __bf16 h[4]; unsigned long long u; } uu;
            uu.h[0] = (__bf16)vv[i][0]; uu.h[1] = (__bf16)vv[i][1];
            uu.h[2] = (__bf16)vv[i][2]; uu.h[3] = (__bf16)vv[i][3];
            *(unsigned long long*)((char*)SC + swz(r, c)) = uu.u;
        }
    }
    __syncthreads();

    // P2: o = (value @ WTv + bv) * wv -> SD
    zero24(acc);
#pragma unroll
    for (int ks = 0; ks < 8; ++ks) {
        int k0 = ks * 32 + q4 * 8;
        bf16x8 a[2], b[4];
#pragma unroll
        for (int mf = 0; mf < 2; ++mf)
            a[mf] = *(const bf16x8*)((const char*)SC + swz(mf * 16 + r16, k0));
#pragma unroll
        for (int nf = 0; nf < 4; ++nf)
            b[nf] = *(const bf16x8*)(WTv + (size_t)(cb + nf * 16 + r16) * 256 + k0);
#pragma unroll
        for (int mf = 0; mf < 2; ++mf)
#pragma unroll
            for (int nf = 0; nf < 4; ++nf)
                acc[mf][nf] = __builtin_amdgcn_mfma_f32_16x16x32_bf16(a[mf], b[nf], acc[mf][nf], 0, 0, 0);
    }
#pragma unroll
    for (int mf = 0; mf < 2; ++mf)
#pragma unroll
        for (int nf = 0; nf < 4; ++nf) {
            int col = cb + nf * 16 + r16;
            float bias = bv[col];
#pragma unroll
            for (int r = 0; r < 4; ++r) {
                int row = mf * 16 + q4 * 4 + r;
                float wvv = wv_s[row * 8 + (col >> 5)];
                *(__bf16*)((char*)SD + swz(row, col)) = (__bf16)((acc[mf][nf][r] + bias) * wvv);
            }
        }
    __syncthreads();

    // P3: out = o @ WTout + bout (streaming store)
    zero24(acc);
#pragma unroll
    for (int ks = 0; ks < 8; ++ks) {
        int k0 = ks * 32 + q4 * 8;
        bf16x8 a[2], b[4];
#pragma unroll
        for (int mf = 0; mf < 2; ++mf)
            a[mf] = *(const bf16x8*)((const char*)SD + swz(mf * 16 + r16, k0));
#pragma unroll
        for (int nf = 0; nf < 4; ++nf)
            b[nf] = *(const bf16x8*)(WTout + (size_t)(cb + nf * 16 + r16) * 256 + k0);
#pragma unroll
        for (int mf = 0; mf < 2; ++mf)
#pragma unroll
            for (int nf = 0; nf < 4; ++nf)
                acc[mf][nf] = __builtin_amdgcn_mfma_f32_16x16x32_bf16(a[mf], b[nf], acc[mf][nf], 0, 0, 0);
    }
#pragma unroll
    for (int mf = 0; mf < 2; ++mf)
#pragma unroll
        for (int nf = 0; nf < 4; ++nf) {
            int col = cb + nf * 16 + r16;
            float bias = bout[col];
#pragma unroll
            for (int r = 0; r < 4; ++r) {
                int row = mf * 16 + q4 * 4 + r;
                __builtin_nontemporal_store(acc[mf][nf][r] + bias,
                                            out + (size_t)(row0 + row) * CC + col);
            }
        }
}

extern "C" void kernel_launch(void* const* d_in, const int* in_sizes, int n_in,
                              void* d_out, int out_size, void* d_ws, size_t ws_size,
                              hipStream_t stream)
{
    const float* query = (const float*)d_in[0];
    const float* key   = (const float*)d_in[1];
    const float* value = (const float*)d_in[2];
    const float* refp  = (const float*)d_in[3];
    const float* pose  = (const float*)d_in[4];
    const float* Wq  = (const float*)d_in[5];  const float* bq   = (const float*)d_in[6];
    const float* Wk  = (const float*)d_in[7];  const float* bk   = (const float*)d_in[8];
    const float* Wv  = (const float*)d_in[9];  const float* bv   = (const float*)d_in[10];
    const float* Wo1 = (const float*)d_in[11]; const float* bo1  = (const float*)d_in[12];
    const float* Wo2 = (const float*)d_in[13]; const float* bo2  = (const float*)d_in[14];
    const float* Wpos= (const float*)d_in[15]; const float* bpos = (const float*)d_in[16];
    const float* Wout= (const float*)d_in[17]; const float* bout = (const float*)d_in[18];

    __bf16* ws = (__bf16*)d_ws;
    float* wv_g = (float*)((char*)d_ws + 1114112);   // 2 MB after weights

    prep_all<<<2176, 256, 0, stream>>>(Wq, Wk, Wpos, Wo1, Wo2, Wv, Wout, ws);

    k1_attn_weights<<<65536 / MT1, 256, 0, stream>>>(
        query, key, pose, refp, ws, bq, bk, bpos, bo1, bo2, wv_g);

    k2_output<<<65536 / MT2, 256, 0, stream>>>(
        value, wv_g, ws, bv, bout, (float*)d_out);
}